// Round 14
// baseline (114.415 us; speedup 1.0000x reference)
//
#include <hip/hip_runtime.h>
#include <math.h>

#define NFFT   1024
#define HOP    256
#define NBANDS 128
#define TFRM   1001
#define BB     16
#define NLEN   256000   // (T-1)*HOP
#define PADL   512
#define QPB    251      // 2-pair (4-frame) blocks per batch: ceil(501/2)

// padded LDS index in float2 units: +1 every 16 breaks radix-4 scatter conflicts
#define PX(a) ((a) + ((a) >> 4))

// ---- fused zeroing + table init ----
// ws[0..511] = interleaved (cos,sin) of exp(-2*pi*i*k/1024); ws[512..1535] =
// Hann*(1/1024).
__global__ __launch_bounds__(256) void zero_and_tables(
    float4* __restrict__ out4, int n4, float* __restrict__ ws)
{
    const int tid = blockIdx.x * 256 + threadIdx.x;
    const float4 z = make_float4(0.0f, 0.0f, 0.0f, 0.0f);
    for (int i = tid; i < n4; i += gridDim.x * 256) out4[i] = z;
    if (tid < 256) {
        float s_, c_;
        sincosf(-6.283185307179586f * (float)tid * (1.0f / 1024.0f), &s_, &c_);
        ws[2 * tid]     = c_;
        ws[2 * tid + 1] = s_;
    } else if (tid < 1280) {
        const int k = tid - 256;
        ws[512 + k] = 0.5f * (1.0f - cosf(6.283185307179586f * (float)k * (1.0f / 1023.0f)))
                      * (1.0f / 1024.0f);
    }
}

// One Stockham radix-4 stage on float2 (re,im) LDS data.
// SGN=-1 forward, +1 inverse (conjugate twiddles, +i).
template<int NS, int SGN>
__device__ __forceinline__ void r4stage2(const float2* __restrict__ x,
                                         float2* __restrict__ y,
                                         const float2* __restrict__ tw, int j) {
    const int m = j & (NS - 1);
    const float2 a0 = x[PX(j)];
    const float2 a1 = x[PX(j + 256)];
    const float2 a2 = x[PX(j + 512)];
    const float2 a3 = x[PX(j + 768)];
    float v1r, v1i, v2r, v2i, v3r, v3i;
    {
        const float2 w = tw[m * (256 / NS)];
        const float wr1 = w.x, wi1 = (SGN < 0) ? w.y : -w.y;
        const float wr2 = wr1 * wr1 - wi1 * wi1, wi2 = 2.0f * wr1 * wi1;
        const float wr3 = wr2 * wr1 - wi2 * wi1, wi3 = wr2 * wi1 + wi2 * wr1;
        v1r = a1.x * wr1 - a1.y * wi1; v1i = a1.x * wi1 + a1.y * wr1;
        v2r = a2.x * wr2 - a2.y * wi2; v2i = a2.x * wi2 + a2.y * wr2;
        v3r = a3.x * wr3 - a3.y * wi3; v3i = a3.x * wi3 + a3.y * wr3;
    }
    const float t0r = a0.x + v2r, t0i = a0.y + v2i;
    const float t1r = a0.x - v2r, t1i = a0.y - v2i;
    const float t2r = v1r + v3r,  t2i = v1i + v3i;
    const float ur  = v1r - v3r,  ui  = v1i - v3i;
    const float t3r = (SGN < 0) ? ui  : -ui;
    const float t3i = (SGN < 0) ? -ur : ur;
    const int d = ((j & ~(NS - 1)) << 2) + m;
    y[PX(d)]          = make_float2(t0r + t2r, t0i + t2i);
    y[PX(d + NS)]     = make_float2(t1r + t3r, t1i + t3i);
    y[PX(d + 2*NS)]   = make_float2(t0r - t2r, t0i - t2i);
    y[PX(d + 3*NS)]   = make_float2(t1r - t3r, t1i - t3i);
}

// fused global load + forward stage 0 (NS=1, no twiddle) into dst
__device__ __forceinline__ void load_stage0(
    const float* __restrict__ nb, int base, int tid,
    bool fast, bool has_b, float2* __restrict__ dst)
{
    float2 a0, a1, a2, a3;
    const int g = base + tid;
    if (fast) {
        // taps 256 apart == HOP: frame_b reuses frame_a's next tap
        const float v0 = __builtin_fmaf(nb[g],        2.0f, -1.0f);
        const float v1 = __builtin_fmaf(nb[g + 256],  2.0f, -1.0f);
        const float v2 = __builtin_fmaf(nb[g + 512],  2.0f, -1.0f);
        const float v3 = __builtin_fmaf(nb[g + 768],  2.0f, -1.0f);
        const float v4 = __builtin_fmaf(nb[g + 1024], 2.0f, -1.0f);
        a0 = make_float2(v0, v1);
        a1 = make_float2(v1, v2);
        a2 = make_float2(v2, v3);
        a3 = make_float2(v3, v4);
    } else {
        #define LD2(gg) make_float2( \
            ((gg) >= 0 && (gg) < NLEN) ? nb[(gg)] * 2.0f - 1.0f : 0.0f, \
            (has_b && (gg) + HOP >= 0 && (gg) + HOP < NLEN) ? nb[(gg) + HOP] * 2.0f - 1.0f : 0.0f)
        a0 = LD2(g); a1 = LD2(g + 256); a2 = LD2(g + 512); a3 = LD2(g + 768);
        #undef LD2
    }
    const float t0r = a0.x + a2.x, t0i = a0.y + a2.y;
    const float t1r = a0.x - a2.x, t1i = a0.y - a2.y;
    const float t2r = a1.x + a3.x, t2i = a1.y + a3.y;
    const float ur  = a1.x - a3.x, ui  = a1.y - a3.y;
    const float t3r = ui, t3i = -ur;           // -i*u (forward)
    const int d = 4 * tid;
    dst[PX(d)]     = make_float2(t0r + t2r, t0i + t2i);
    dst[PX(d + 1)] = make_float2(t1r + t3r, t1i + t3i);
    dst[PX(d + 2)] = make_float2(t0r - t2r, t0i - t2i);
    dst[PX(d + 3)] = make_float2(t1r - t3r, t1i - t3i);
}

// fused Hermitian unpack + per-frame filter + inverse stage 0 (NS=1): src->dst
// W[k] = ga*Fa + i*gb*Fb, Fa=(Z[k]+conj(Z[N-k]))/2, Fb=-i(Z[k]-conj(Z[N-k]))/2
__device__ __forceinline__ void herm_inv0(
    const float2* __restrict__ src, float2* __restrict__ dst,
    const float2* __restrict__ gab, int tid)
{
    float2 W[4];
    #pragma unroll
    for (int c = 0; c < 4; ++c) {
        const int k = tid + 256 * c;
        const float2 z1 = src[PX(k)];
        const float2 z2 = src[PX((NFFT - k) & (NFFT - 1))];
        if (k == 0) {
            W[c] = make_float2(0.0f, 0.0f);
        } else {
            const int jm = (k < NFFT - k) ? k : NFFT - k;
            const float2 g = gab[(jm - 1) >> 2];
            const float Far = 0.5f * (z1.x + z2.x), Fai = 0.5f * (z1.y - z2.y);
            const float Fbr = 0.5f * (z1.y + z2.y), Fbi = 0.5f * (z2.x - z1.x);
            W[c] = make_float2(g.x * Far - g.y * Fbi, g.x * Fai + g.y * Fbr);
        }
    }
    const float t0r = W[0].x + W[2].x, t0i = W[0].y + W[2].y;
    const float t1r = W[0].x - W[2].x, t1i = W[0].y - W[2].y;
    const float t2r = W[1].x + W[3].x, t2i = W[1].y + W[3].y;
    const float ur  = W[1].x - W[3].x, ui  = W[1].y - W[3].y;
    const float t3r = -ui, t3i = ur;           // +i*u (inverse)
    const int d = 4 * tid;
    dst[PX(d)]     = make_float2(t0r + t2r, t0i + t2i);
    dst[PX(d + 1)] = make_float2(t1r + t3r, t1i + t3i);
    dst[PX(d + 2)] = make_float2(t0r - t2r, t0i - t2i);
    dst[PX(d + 3)] = make_float2(t1r - t3r, t1i - t3i);
}

// fused inverse stage NS=256 (outputs land at k = tid + 256c exactly)
__device__ __forceinline__ void inv_final(
    const float2* __restrict__ src, const float2* __restrict__ tw, int tid,
    float2 r[4])
{
    const float2 c0 = src[PX(tid)];
    const float2 c1 = src[PX(tid + 256)];
    const float2 c2 = src[PX(tid + 512)];
    const float2 c3 = src[PX(tid + 768)];
    const float2 w = tw[tid];
    const float wr1 = w.x, wi1 = -w.y;         // conjugate (inverse)
    const float wr2 = wr1 * wr1 - wi1 * wi1, wi2 = 2.0f * wr1 * wi1;
    const float wr3 = wr2 * wr1 - wi2 * wi1, wi3 = wr2 * wi1 + wi2 * wr1;
    const float v1r = c1.x * wr1 - c1.y * wi1, v1i = c1.x * wi1 + c1.y * wr1;
    const float v2r = c2.x * wr2 - c2.y * wi2, v2i = c2.x * wi2 + c2.y * wr2;
    const float v3r = c3.x * wr3 - c3.y * wi3, v3i = c3.x * wi3 + c3.y * wr3;
    const float t0r = c0.x + v2r, t0i = c0.y + v2i;
    const float t1r = c0.x - v2r, t1i = c0.y - v2i;
    const float t2r = v1r + v3r,  t2i = v1i + v3i;
    const float ur  = v1r - v3r,  ui  = v1i - v3i;
    const float t3r = -ui, t3i = ur;           // +i*u (inverse)
    r[0] = make_float2(t0r + t2r, t0i + t2i);
    r[1] = make_float2(t1r + t3r, t1i + t3i);
    r[2] = make_float2(t0r - t2r, t0i - t2i);
    r[3] = make_float2(t1r - t3r, t1i - t3i);
}

// ---- main kernel: one block (256 threads) per 2 FRAME PAIRS (4 frames) ----
// Two independent FFT pipelines (A: pair 2q, B: pair 2q+1) interleaved at
// stage granularity: each barrier serves both (9 barriers / 2 pairs), and each
// thread runs two independent butterfly chains (ILP x2 hides LDS latency).
// Register OLA s[7]: frame 4q+f sample k=tid+256c -> slot f+c. Slot 3 is
// block-complete (4/4 contributions) and its residue class [256,512) mod 1024
// is touched by NO other block -> plain store; others atomic (6/thread).
// XCD-chunked swizzle: 4016 = 8 XCDs x 502 = 2 whole batches per XCD.
__global__ __launch_bounds__(256) void fn_kernel(
    const float* __restrict__ fb,     // (B, 1, 128, T)
    const float* __restrict__ noise,  // (B, 1, NLEN)
    const float* __restrict__ tbl,    // d_ws tables from zero_and_tables
    float* __restrict__ out)          // (B, 1, NLEN), pre-zeroed
{
    __shared__ float2 bA0[1087], bA1[1087], bB0[1087], bB1[1087];
    __shared__ float2 tw[256];
    __shared__ float2 gabA[128], gabB[128];

    const int tid = threadIdx.x;
    const int hw  = blockIdx.x;
    const int blk = (hw & 7) * 502 + (hw >> 3);   // bijective: 4016 = 8*502
    const int b   = blk / QPB;
    const int q   = blk - b * QPB;                // 4-frame group within batch
    // interior: both pairs' fast-path loads in-bounds (pairs 2q,2q+1 in [1,498])
    // AND all 7 OLA slots in-bounds: q in [1,248]
    const bool interior = (q >= 1) & (q <= 248);
    const int  f0 = 4 * q;                        // first frame id of block
    const bool has_bA = (f0 + 1) < TFRM;
    const bool validB = (f0 + 2) < TFRM;
    const bool has_bB = (f0 + 3) < TFRM;

    tw[tid] = ((const float2*)tbl)[tid & 255];
    if (tid < NBANDS) {
        const size_t off = (size_t)b * (NBANDS * TFRM) + (size_t)tid * TFRM + f0;
        gabA[tid] = make_float2(fb[off], has_bA ? fb[off + 1] : 0.0f);
        gabB[tid] = make_float2(validB ? fb[off + 2] : 0.0f,
                                has_bB ? fb[off + 3] : 0.0f);
    }

    const float* nb = noise + (size_t)b * NLEN;
    const int base_a = 1024 * q - PADL;           // pair A frame_a OLA origin

    load_stage0(nb, base_a,       tid, interior, has_bA, bA0);
    load_stage0(nb, base_a + 512, tid, interior, has_bB, bB0);
    __syncthreads();

    // ---- forward stages NS=4..256 (dual) ----
    r4stage2<4,   -1>(bA0, bA1, tw, tid); r4stage2<4,   -1>(bB0, bB1, tw, tid); __syncthreads();
    r4stage2<16,  -1>(bA1, bA0, tw, tid); r4stage2<16,  -1>(bB1, bB0, tw, tid); __syncthreads();
    r4stage2<64,  -1>(bA0, bA1, tw, tid); r4stage2<64,  -1>(bB0, bB1, tw, tid); __syncthreads();
    r4stage2<256, -1>(bA1, bA0, tw, tid); r4stage2<256, -1>(bB1, bB0, tw, tid); __syncthreads();
    // Z_A in bA0, Z_B in bB0

    // ---- Hermitian + filter + inverse stage 0 (dual) ----
    herm_inv0(bA0, bA1, gabA, tid); herm_inv0(bB0, bB1, gabB, tid); __syncthreads();

    // ---- inverse stages NS=4..64 (dual) ----
    r4stage2<4,  +1>(bA1, bA0, tw, tid); r4stage2<4,  +1>(bB1, bB0, tw, tid); __syncthreads();
    r4stage2<16, +1>(bA0, bA1, tw, tid); r4stage2<16, +1>(bB0, bB1, tw, tid); __syncthreads();
    r4stage2<64, +1>(bA1, bA0, tw, tid); r4stage2<64, +1>(bB1, bB0, tw, tid); __syncthreads();

    // ---- final inverse stage (register) + window + 7-slot merged OLA ----
    float2 rA[4], rB[4];
    inv_final(bA0, tw, tid, rA);
    inv_final(bB0, tw, tid, rB);

    const float* win = tbl + 512;
    float wv[4];
    #pragma unroll
    for (int c = 0; c < 4; ++c) wv[c] = win[tid + 256 * c];

    // frame 4q+f, sample k=tid+256c -> block slot f+c (f: A.x=0 A.y=1 B.x=2 B.y=3)
    float s[7];
    #pragma unroll
    for (int i = 0; i < 7; ++i) s[i] = 0.0f;
    #pragma unroll
    for (int c = 0; c < 4; ++c) {
        s[c]     += rA[c].x * wv[c];
        s[c + 1] += rA[c].y * wv[c];
        s[c + 2] += rB[c].x * wv[c];
        s[c + 3] += rB[c].y * wv[c];
    }

    float* ob = out + (size_t)b * NLEN;
    if (interior) {
        #pragma unroll
        for (int c = 0; c < 7; ++c) {
            const int pos = base_a + tid + 256 * c;
            if (c == 3) ob[pos] = s[3];           // block-complete slot
            else atomicAdd(&ob[pos], s[c]);       // shared with neighbors
        }
    } else {
        #pragma unroll
        for (int c = 0; c < 7; ++c) {
            const int pos = base_a + tid + 256 * c;
            if (pos >= 0 && pos < NLEN) {
                if (c == 3) ob[pos] = s[3];
                else atomicAdd(&ob[pos], s[c]);
            }
        }
    }
}

extern "C" void kernel_launch(void* const* d_in, const int* in_sizes, int n_in,
                              void* d_out, int out_size, void* d_ws, size_t ws_size,
                              hipStream_t stream) {
    const float* fb    = (const float*)d_in[0];  // (16,1,128,1001) fp32
    const float* noise = (const float*)d_in[1];  // (16,1,256000)   fp32
    float* out = (float*)d_out;                  // (16,1,256000)   fp32
    float* tbl = (float*)d_ws;                   // 1536 floats = 6 KB

    // Fused zero+tables (out_size = 4,096,000 floats = 1,024,000 float4)
    zero_and_tables<<<2048, 256, 0, stream>>>((float4*)out, out_size / 4, tbl);

    const int grid = BB * QPB;  // 4016 blocks = 8 XCDs x 502
    fn_kernel<<<grid, 256, 0, stream>>>(fb, noise, tbl, out);
}